// Round 7
// baseline (95633.575 us; speedup 1.0000x reference)
//
#include <hip/hip_runtime.h>
#include <hip/hip_bf16.h>

#define TSEQ 65536
#define INPUT_SIZE 128
#define HIDDEN 100
#define GATES 400    // 4*HIDDEN
#define T_ABL 720896 // diagnostic skeleton steps (11x TSEQ, so it tops rocprof table)

typedef __attribute__((ext_vector_type(8))) short bf16x8;
typedef __attribute__((ext_vector_type(4))) float f32x4;

__device__ __forceinline__ unsigned short f2bf(float x) {
    union { float f; unsigned int u; } v; v.f = x;
    unsigned int r = v.u + 0x7fffu + ((v.u >> 16) & 1u);
    return (unsigned short)(r >> 16);
}
// 1-instruction RNE f32->bf16 (no builtin on gfx950; T12 recipe)
__device__ __forceinline__ unsigned short f2bf_fast(float x) {
    unsigned int r;
    asm("v_cvt_pk_bf16_f32 %0, %1, %2" : "=v"(r) : "v"(x), "v"(0.0f));
    return (unsigned short)r;
}
__device__ __forceinline__ float bf2f(unsigned int u) {
    union { unsigned int u; float f; } v; v.u = u << 16; return v.f;
}
__device__ __forceinline__ float rcp_fast(float x) { return __builtin_amdgcn_rcpf(x); }
__device__ __forceinline__ float sigm(float x) { return rcp_fast(1.0f + __expf(-x)); }
__device__ __forceinline__ float tanh_fast(float x) {
    return 1.0f - 2.0f * rcp_fast(__expf(2.0f * x) + 1.0f);
}

// barrier without vmcnt drain: LDS-drain + s_barrier + compiler memory fence
#define LDS_BARRIER()                                              \
    do {                                                           \
        asm volatile("s_waitcnt lgkmcnt(0)" ::: "memory");         \
        __builtin_amdgcn_s_barrier();                              \
        asm volatile("" ::: "memory");                             \
    } while (0)

// ---------------------------------------------------------------------------
// Kernel 1: xp_perm[t][4*u + g] = b_ih[j] + b_hh[j] + sum_k x[t][k]*W_ih[j][k]
// where j = g*100 + u. Unit-major/gate-minor layout.
// ---------------------------------------------------------------------------
__global__ __launch_bounds__(256) void xproj_kernel(
    const float* __restrict__ x,     // [TSEQ][128]
    const float* __restrict__ W,     // [400][128]
    const float* __restrict__ bi,    // [400]
    const float* __restrict__ bh,    // [400]
    float* __restrict__ xp)          // [TSEQ][400] (permuted)
{
    __shared__ __align__(16) float xs[16 * 128];
    const int tid = threadIdx.x;
    const int t0 = blockIdx.x * 16;

#pragma unroll
    for (int i = 0; i < 8; ++i)
        xs[i * 256 + tid] = x[(size_t)t0 * 128 + i * 256 + tid];
    __syncthreads();

    const int j1 = tid;
    const int j2 = tid + 256;
    const bool has2 = (j2 < GATES);
    const int p1 = 4 * (j1 % 100) + (j1 / 100);
    const int p2 = has2 ? (4 * (j2 % 100) + (j2 / 100)) : 0;

    float acc1[16], acc2[16];
    const float bias1 = bi[j1] + bh[j1];
    const float bias2 = has2 ? (bi[j2] + bh[j2]) : 0.0f;
#pragma unroll
    for (int tt = 0; tt < 16; ++tt) { acc1[tt] = bias1; acc2[tt] = bias2; }

    const float4* W4 = reinterpret_cast<const float4*>(W);
    const float4* xs4 = reinterpret_cast<const float4*>(xs);

    for (int kk = 0; kk < 32; ++kk) {
        const float4 wa = W4[(size_t)j1 * 32 + kk];
        float4 wb = make_float4(0.f, 0.f, 0.f, 0.f);
        if (has2) wb = W4[(size_t)j2 * 32 + kk];
#pragma unroll
        for (int tt = 0; tt < 16; ++tt) {
            const float4 xv = xs4[tt * 32 + kk];
            acc1[tt] = fmaf(wa.x, xv.x, acc1[tt]);
            acc1[tt] = fmaf(wa.y, xv.y, acc1[tt]);
            acc1[tt] = fmaf(wa.z, xv.z, acc1[tt]);
            acc1[tt] = fmaf(wa.w, xv.w, acc1[tt]);
            acc2[tt] = fmaf(wb.x, xv.x, acc2[tt]);
            acc2[tt] = fmaf(wb.y, xv.y, acc2[tt]);
            acc2[tt] = fmaf(wb.z, xv.z, acc2[tt]);
            acc2[tt] = fmaf(wb.w, xv.w, acc2[tt]);
        }
    }

#pragma unroll
    for (int tt = 0; tt < 16; ++tt) {
        xp[(size_t)(t0 + tt) * GATES + p1] = acc1[tt];
        if (has2) xp[(size_t)(t0 + tt) * GATES + p2] = acc2[tt];
    }
}

// ---------------------------------------------------------------------------
// DIAGNOSTIC: sync skeleton only. Same 8-wave/512-thread shape, same LDS
// footprint, same per-step pattern (4x ds_read_b128 of h -> dependent VALU ->
// cell-lane ds_write of h -> lgkm drain + s_barrier), NO MFMA / cell math /
// global ops. 720896 steps so its replays top the rocprof table. Writes a
// sink into a region the real recurrence fully overwrites afterwards.
// ---------------------------------------------------------------------------
__global__ __launch_bounds__(512, 1) void skel_kernel(unsigned short* __restrict__ dummy)
{
    __shared__ __align__(16) unsigned short h_lds[2][128];
    const int tid = threadIdx.x;
    const int lane = tid & 63;
    const int w = tid >> 6;
    const int bq = lane >> 4;
    const int m = lane & 15;
    const bool cell = (m < 3) || (w == 7 && m == 3);
    const int unit = 12 * w + 4 * m + bq;

    if (tid < 128) { h_lds[0][tid] = 0; h_lds[1][tid] = 0; }
    __syncthreads();

    for (int t = 0; t < T_ABL; t += 4) {
#pragma unroll
        for (int u = 0; u < 4; ++u) {
            const int cur = u & 1;
            const uint4 b0 = *(const uint4*)&h_lds[cur][0 * 32 + bq * 8];
            const uint4 b1 = *(const uint4*)&h_lds[cur][1 * 32 + bq * 8];
            const uint4 b2 = *(const uint4*)&h_lds[cur][2 * 32 + bq * 8];
            const uint4 b3 = *(const uint4*)&h_lds[cur][3 * 32 + bq * 8];
            const unsigned int s = b0.x + b1.y + b2.z + b3.w;   // dep chain stays real
            if (cell) h_lds[1 - cur][unit] = (unsigned short)(s + (unsigned)u);
            LDS_BARRIER();
        }
    }
    dummy[tid] = (unsigned short)(h_lds[0][tid & 127] + tid);   // sink (overwritten later)
}

// ---------------------------------------------------------------------------
// Kernel 2: LSTM recurrence (real). One block, 512 threads (8 waves),
// 1 barrier/step, zero preact LDS traffic (broadcast-D trick), chained
// 4-MFMA accumulation per tile, cvt_pk for the h bf16 conversion.
// ---------------------------------------------------------------------------
__global__ __launch_bounds__(512, 1) void lstm_rec_kernel(
    const float* __restrict__ xp,    // [TSEQ][400] permuted, includes biases
    const float* __restrict__ Whh,   // [400][100] original layout
    unsigned short* __restrict__ hs) // [TSEQ][100] bf16
{
    __shared__ __align__(16) unsigned short h_lds[2][128];  // bf16 h, zero-padded

    const int tid = threadIdx.x;
    const int lane = tid & 63;
    const int w = tid >> 6;          // wave 0..7
    const int bq = lane >> 4;        // k-group AND D row-group q (0..3)
    const int m = lane & 15;         // A row within tile / D col

    // ---- A fragments: 4 tile-slots (wave w: tiles 3w..3w+2; slot 3 = tile 24, w7 only)
    bf16x8 afrag[4][4];
#pragma unroll
    for (int i = 0; i < 4; ++i) {
        const int ti = (i < 3) ? (3 * w + i) : 24;
        const bool valid = (i < 3) || (w == 7);
        const int g = m & 3;                  // permuted tile-row -> gate
        const int uu = 4 * ti + (m >> 2);     // -> hidden unit
        const int orow = g * 100 + uu;        // original W_hh row
#pragma unroll
        for (int kk = 0; kk < 4; ++kk) {
            float vals[8];
            if (valid && kk < 3) {
                const float4 w0 = *(const float4*)&Whh[(size_t)orow * 100 + kk * 32 + bq * 8];
                const float4 w1 = *(const float4*)&Whh[(size_t)orow * 100 + kk * 32 + bq * 8 + 4];
                vals[0] = w0.x; vals[1] = w0.y; vals[2] = w0.z; vals[3] = w0.w;
                vals[4] = w1.x; vals[5] = w1.y; vals[6] = w1.z; vals[7] = w1.w;
            } else if (valid && bq == 0) {    // kk==3: k=96..103, only 96..99 real
                const float4 w0 = *(const float4*)&Whh[(size_t)orow * 100 + 96];
                vals[0] = w0.x; vals[1] = w0.y; vals[2] = w0.z; vals[3] = w0.w;
                vals[4] = 0.f; vals[5] = 0.f; vals[6] = 0.f; vals[7] = 0.f;
            } else {
#pragma unroll
                for (int j = 0; j < 8; ++j) vals[j] = 0.f;
            }
#pragma unroll
            for (int j = 0; j < 8; ++j) afrag[i][kk][j] = (short)f2bf(vals[j]);
        }
    }

    // ---- cell-lane mapping: lane (q=bq, m) handles unit 4*tile(slot m)+q
    const bool cell = (m < 3) || (w == 7 && m == 3);
    const int unit = 12 * w + 4 * m + bq;     // valid when `cell` (<100)

    // ---- init
    if (tid < 128) { h_lds[0][tid] = 0; h_lds[1][tid] = 0; }
    float c = 0.0f;
    float4 xpv[4];
    if (cell) {
#pragma unroll
        for (int p = 0; p < 4; ++p)
            xpv[p] = *(const float4*)&xp[(size_t)p * GATES + 4 * unit];
    }
    __syncthreads();

    for (int t = 0; t < TSEQ; t += 4) {
#pragma unroll
        for (int u = 0; u < 4; ++u) {
            const int tt = t + u;
            const int cur = u & 1;           // parity of tt == parity of u

            // ---- B fragments: h broadcast, 16B LDS reads (conflict-free)
            bf16x8 bfr[4];
#pragma unroll
            for (int kk = 0; kk < 4; ++kk) {
                const uint4 braw = *(const uint4*)&h_lds[cur][kk * 32 + bq * 8];
                bfr[kk] = __builtin_bit_cast(bf16x8, braw);
            }

            // ---- MFMA: single chained accumulator per tile (3-4 indep chains)
            f32x4 pa_s[4];
#pragma unroll
            for (int i = 0; i < 4; ++i) {
                if (i < 3 || w == 7) {
                    f32x4 acc = {0.f, 0.f, 0.f, 0.f};
                    acc = __builtin_amdgcn_mfma_f32_16x16x32_bf16(afrag[i][0], bfr[0], acc, 0, 0, 0);
                    acc = __builtin_amdgcn_mfma_f32_16x16x32_bf16(afrag[i][1], bfr[1], acc, 0, 0, 0);
                    acc = __builtin_amdgcn_mfma_f32_16x16x32_bf16(afrag[i][2], bfr[2], acc, 0, 0, 0);
                    acc = __builtin_amdgcn_mfma_f32_16x16x32_bf16(afrag[i][3], bfr[3], acc, 0, 0, 0);
                    pa_s[i] = acc;
                } else {
                    pa_s[i] = (f32x4){0.f, 0.f, 0.f, 0.f};
                }
            }

            // ---- slot select (all-register, static indices) + cell update
            f32x4 pa = pa_s[0];
            pa = (m == 1) ? pa_s[1] : pa;
            pa = (m == 2) ? pa_s[2] : pa;
            if (w == 7) pa = (m == 3) ? pa_s[3] : pa;

            if (cell) {
                const float4 xq = xpv[u];
                const float gi = sigm(pa.x + xq.x);
                const float gf = sigm(pa.y + xq.y);
                const float gg = tanh_fast(pa.z + xq.z);
                const float go = sigm(pa.w + xq.w);
                c = fmaf(gf, c, gi * gg);
                const float hv = go * tanh_fast(c);
                const unsigned short hb = f2bf_fast(hv);
                h_lds[1 - cur][unit] = hb;                     // publish
                hs[(size_t)tt * HIDDEN + unit] = hb;           // fire-and-forget bf16
                if (tt + 4 < TSEQ)                             // depth-4 prefetch
                    xpv[u] = *(const float4*)&xp[(size_t)(tt + 4) * GATES + 4 * unit];
            }
            LDS_BARRIER();   // h visible to all waves for step tt+1
        }
    }
}

// ---------------------------------------------------------------------------
// Kernel 3: out[t] = sigmoid(dot(hs_bf16[t], W_lin) + b_lin)
// ---------------------------------------------------------------------------
__global__ __launch_bounds__(256) void pred_kernel(
    const unsigned short* __restrict__ hs,   // [TSEQ][100] bf16
    const float* __restrict__ wlin,          // [100]
    const float* __restrict__ blin,          // [1]
    float* __restrict__ out)                 // [TSEQ]
{
    __shared__ __align__(16) float wl[HIDDEN];
    const int tid = threadIdx.x;
    if (tid < HIDDEN) wl[tid] = wlin[tid];
    __syncthreads();

    const int t = blockIdx.x * 256 + tid;
    const unsigned short* hrow = hs + (size_t)t * HIDDEN;   // 8B-aligned
    float acc = blin[0];
#pragma unroll
    for (int kk = 0; kk < 25; ++kk) {                       // 25 x uint2 = 100 bf16
        const uint2 v = *(const uint2*)&hrow[kk * 4];
        acc = fmaf(bf2f(v.x & 0xffffu), wl[kk * 4 + 0], acc);
        acc = fmaf(bf2f(v.x >> 16),     wl[kk * 4 + 1], acc);
        acc = fmaf(bf2f(v.y & 0xffffu), wl[kk * 4 + 2], acc);
        acc = fmaf(bf2f(v.y >> 16),     wl[kk * 4 + 3], acc);
    }
    out[t] = sigm(acc);
}

// ---------------------------------------------------------------------------
extern "C" void kernel_launch(void* const* d_in, const int* in_sizes, int n_in,
                              void* d_out, int out_size, void* d_ws, size_t ws_size,
                              hipStream_t stream) {
    const float* x     = (const float*)d_in[0];  // [65536,128]
    const float* W_ih  = (const float*)d_in[1];  // [400,128]
    const float* W_hh  = (const float*)d_in[2];  // [400,100]
    const float* b_ih  = (const float*)d_in[3];  // [400]
    const float* b_hh  = (const float*)d_in[4];  // [400]
    const float* W_lin = (const float*)d_in[5];  // [1,100]
    const float* b_lin = (const float*)d_in[6];  // [1]
    float* out = (float*)d_out;                  // [65536]

    float* xp = (float*)d_ws;                                  // [TSEQ*400] fp32
    unsigned short* hs = (unsigned short*)(xp + (size_t)TSEQ * GATES);  // [TSEQ*100] bf16

    xproj_kernel<<<TSEQ / 16, 256, 0, stream>>>(x, W_ih, b_ih, b_hh, xp);
    // DIAGNOSTIC dispatch: sync-skeleton cost. Writes into hs region, which the
    // real recurrence below fully overwrites -> correctness unaffected.
    skel_kernel<<<1, 512, 0, stream>>>(hs);
    lstm_rec_kernel<<<1, 512, 0, stream>>>(xp, W_hh, hs);
    pred_kernel<<<TSEQ / 256, 256, 0, stream>>>(hs, W_lin, b_lin, out);
}

// Round 8
// 23442.741 us; speedup vs baseline: 4.0795x; 4.0795x over previous
//
#include <hip/hip_runtime.h>
#include <hip/hip_bf16.h>

#define TSEQ 65536
#define INPUT_SIZE 128
#define HIDDEN 100
#define GATES 400   // 4*HIDDEN

typedef __attribute__((ext_vector_type(8))) short bf16x8;
typedef __attribute__((ext_vector_type(4))) float f32x4;

__device__ __forceinline__ unsigned short f2bf(float x) {
    union { float f; unsigned int u; } v; v.f = x;
    unsigned int r = v.u + 0x7fffu + ((v.u >> 16) & 1u);
    return (unsigned short)(r >> 16);
}
// 1-instruction RNE f32->bf16
__device__ __forceinline__ unsigned short f2bf_fast(float x) {
    unsigned int r;
    asm("v_cvt_pk_bf16_f32 %0, %1, %2" : "=v"(r) : "v"(x), "v"(0.0f));
    return (unsigned short)r;
}
__device__ __forceinline__ float bf2f(unsigned int u) {
    union { unsigned int u; float f; } v; v.u = u << 16; return v.f;
}
__device__ __forceinline__ float rcp_fast(float x) { return __builtin_amdgcn_rcpf(x); }
__device__ __forceinline__ float sigm(float x) { return rcp_fast(1.0f + __expf(-x)); }

// DPP quad_perm broadcast within groups of 4 lanes (pure VALU, no LDS).
// CTRL: quad_perm[a,a,a,a] = a*0x55 (0x00 -> lane0 of quad, 0x55 -> lane1, 0xAA -> lane2)
template <int CTRL>
__device__ __forceinline__ float qb(float v) {
    int i = __builtin_bit_cast(int, v);
    int r = __builtin_amdgcn_mov_dpp(i, CTRL, 0xF, 0xF, true);
    return __builtin_bit_cast(float, r);
}

// barrier without vmcnt drain: LDS-drain + s_barrier + compiler memory fence
#define LDS_BARRIER()                                              \
    do {                                                           \
        asm volatile("s_waitcnt lgkmcnt(0)" ::: "memory");         \
        __builtin_amdgcn_s_barrier();                              \
        asm volatile("" ::: "memory");                             \
    } while (0)

// ---------------------------------------------------------------------------
// Kernel 1: xp_perm[t][p] = b_ih[j] + b_hh[j] + sum_k x[t][k]*W_ih[j][k]
// Permutation now matches the MFMA tile-column layout of the recurrence:
// orig row j = g*100 + u  ->  p = 16*(u>>2) + 4*(u&3) + g
// (tile ti = u>>2 covers columns 16ti..16ti+15; col = 4*(u&3)+g)
// ---------------------------------------------------------------------------
__global__ __launch_bounds__(256) void xproj_kernel(
    const float* __restrict__ x,     // [TSEQ][128]
    const float* __restrict__ W,     // [400][128]
    const float* __restrict__ bi,    // [400]
    const float* __restrict__ bh,    // [400]
    float* __restrict__ xp)          // [TSEQ][400] (permuted)
{
    __shared__ __align__(16) float xs[16 * 128];
    const int tid = threadIdx.x;
    const int t0 = blockIdx.x * 16;

#pragma unroll
    for (int i = 0; i < 8; ++i)
        xs[i * 256 + tid] = x[(size_t)t0 * 128 + i * 256 + tid];
    __syncthreads();

    const int j1 = tid;
    const int j2 = tid + 256;
    const bool has2 = (j2 < GATES);
    const int u1 = j1 % 100, g1 = j1 / 100;
    const int p1 = 16 * (u1 >> 2) + 4 * (u1 & 3) + g1;
    const int u2 = has2 ? (j2 % 100) : 0, g2 = has2 ? (j2 / 100) : 0;
    const int p2 = 16 * (u2 >> 2) + 4 * (u2 & 3) + g2;

    float acc1[16], acc2[16];
    const float bias1 = bi[j1] + bh[j1];
    const float bias2 = has2 ? (bi[j2] + bh[j2]) : 0.0f;
#pragma unroll
    for (int tt = 0; tt < 16; ++tt) { acc1[tt] = bias1; acc2[tt] = bias2; }

    const float4* W4 = reinterpret_cast<const float4*>(W);
    const float4* xs4 = reinterpret_cast<const float4*>(xs);

    for (int kk = 0; kk < 32; ++kk) {
        const float4 wa = W4[(size_t)j1 * 32 + kk];
        float4 wb = make_float4(0.f, 0.f, 0.f, 0.f);
        if (has2) wb = W4[(size_t)j2 * 32 + kk];
#pragma unroll
        for (int tt = 0; tt < 16; ++tt) {
            const float4 xv = xs4[tt * 32 + kk];
            acc1[tt] = fmaf(wa.x, xv.x, acc1[tt]);
            acc1[tt] = fmaf(wa.y, xv.y, acc1[tt]);
            acc1[tt] = fmaf(wa.z, xv.z, acc1[tt]);
            acc1[tt] = fmaf(wa.w, xv.w, acc1[tt]);
            acc2[tt] = fmaf(wb.x, xv.x, acc2[tt]);
            acc2[tt] = fmaf(wb.y, xv.y, acc2[tt]);
            acc2[tt] = fmaf(wb.z, xv.z, acc2[tt]);
            acc2[tt] = fmaf(wb.w, xv.w, acc2[tt]);
        }
    }

#pragma unroll
    for (int tt = 0; tt < 16; ++tt) {
        xp[(size_t)(t0 + tt) * GATES + p1] = acc1[tt];
        if (has2) xp[(size_t)(t0 + tt) * GATES + p2] = acc2[tt];
    }
}

// ---------------------------------------------------------------------------
// Kernel 2: LSTM recurrence. One block, 512 threads (8 waves), 1 barrier/step.
// TRANSPOSED MFMA: D = A*B with A = h replicated over rows, B = W-tile
// (col j of tile ti = original gate row (j&3)*100 + 4*ti + (j>>2)).
// => D[r][col m] = preact of gate-column m, identical for all r: each lane
// holds ONE scalar gate preact (acc[0]) -- no f32x4 slot-select needed.
// Lane (bq, m): tile 3w+bq (w7,bq3 -> 24), col m; unit = 4*tile + (m>>2),
// gate g = m&3. The 4 gates of a unit sit in 4 ADJACENT lanes (quad) =>
// cross-gate combine via 3 DPP quad_perm broadcasts. Per-wave trans work:
// 4 (was 10). Cell state c lives on g==1 lanes; h written by g==3 lanes.
// ---------------------------------------------------------------------------
__global__ __launch_bounds__(512, 1) void lstm_rec_kernel(
    const float* __restrict__ xp,    // [TSEQ][400] permuted, includes biases
    const float* __restrict__ Whh,   // [400][100] original layout
    unsigned short* __restrict__ hs) // [TSEQ][100] bf16
{
    __shared__ __align__(16) unsigned short h_lds[2][128];  // bf16 h, zero-padded

    const int tid = threadIdx.x;
    const int lane = tid & 63;
    const int w = tid >> 6;          // wave 0..7
    const int bq = lane >> 4;        // k-chunk for frags; tile-slot for cell phase
    const int m = lane & 15;         // B col within tile = gate index in tile
    const int g = m & 3;             // gate: 0=i 1=f 2=g~ 3=o

    // ---- W fragments (B operand): 4 tile-slots (wave w: tiles 3w..3w+2; slot 3 = tile 24, w7)
    bf16x8 wfrag[4][4];
#pragma unroll
    for (int i = 0; i < 4; ++i) {
        const int ti = (i < 3) ? (3 * w + i) : 24;
        const bool valid = (i < 3) || (w == 7);
        const int uu = 4 * ti + (m >> 2);     // hidden unit of col m
        const int orow = g * 100 + uu;        // original W_hh row
#pragma unroll
        for (int kk = 0; kk < 4; ++kk) {
            float vals[8];
            if (valid && kk < 3) {
                const float4 w0 = *(const float4*)&Whh[(size_t)orow * 100 + kk * 32 + bq * 8];
                const float4 w1 = *(const float4*)&Whh[(size_t)orow * 100 + kk * 32 + bq * 8 + 4];
                vals[0] = w0.x; vals[1] = w0.y; vals[2] = w0.z; vals[3] = w0.w;
                vals[4] = w1.x; vals[5] = w1.y; vals[6] = w1.z; vals[7] = w1.w;
            } else if (valid && bq == 0) {    // kk==3: k=96..103, only 96..99 real
                const float4 w0 = *(const float4*)&Whh[(size_t)orow * 100 + 96];
                vals[0] = w0.x; vals[1] = w0.y; vals[2] = w0.z; vals[3] = w0.w;
                vals[4] = 0.f; vals[5] = 0.f; vals[6] = 0.f; vals[7] = 0.f;
            } else {
#pragma unroll
                for (int j = 0; j < 8; ++j) vals[j] = 0.f;
            }
#pragma unroll
            for (int j = 0; j < 8; ++j) wfrag[i][kk][j] = (short)f2bf(vals[j]);
        }
    }

    // ---- lane roles (all loop-invariant, hoisted)
    const int mytile = (bq < 3) ? (3 * w + bq) : 24;   // tile this lane activates
    const int unit = 4 * mytile + (m >> 2);            // unit of this lane's quad
    const int pown = 16 * mytile + m;                  // permuted xp index of this gate
    const bool qvalid = (bq < 3) || (w == 7);
    const bool writer = qvalid && (g == 3);
    const float kk2 = (g == 2) ? 2.0f : 1.0f;          // tanh uses exp(2x)
    const float bsub = (g == 2) ? 2.0f : 1.0f;         // act = 1 - bsub/(e+1)
    const bool isg1 = (g == 1);

    // ---- init
    if (tid < 128) { h_lds[0][tid] = 0; h_lds[1][tid] = 0; }
    float c = 0.0f;
    float xqv[4];
#pragma unroll
    for (int p = 0; p < 4; ++p)
        xqv[p] = xp[(size_t)p * GATES + pown];
    __syncthreads();

    for (int t = 0; t < TSEQ; t += 4) {
#pragma unroll
        for (int u = 0; u < 4; ++u) {
            const int tt = t + u;
            const int cur = u & 1;           // parity of tt == parity of u

            // ---- A fragments (h replicated): 16B LDS broadcast reads
            bf16x8 bfr[4];
#pragma unroll
            for (int kk = 0; kk < 4; ++kk) {
                const uint4 braw = *(const uint4*)&h_lds[cur][kk * 32 + bq * 8];
                bfr[kk] = __builtin_bit_cast(bf16x8, braw);
            }

            // ---- MFMA: D = h_repl * W_tile ; all 4 D regs identical per lane
            f32x4 acc_s[4];
#pragma unroll
            for (int i = 0; i < 4; ++i) {
                if (i < 3 || w == 7) {
                    f32x4 acc = {0.f, 0.f, 0.f, 0.f};
                    acc = __builtin_amdgcn_mfma_f32_16x16x32_bf16(bfr[0], wfrag[i][0], acc, 0, 0, 0);
                    acc = __builtin_amdgcn_mfma_f32_16x16x32_bf16(bfr[1], wfrag[i][1], acc, 0, 0, 0);
                    acc = __builtin_amdgcn_mfma_f32_16x16x32_bf16(bfr[2], wfrag[i][2], acc, 0, 0, 0);
                    acc = __builtin_amdgcn_mfma_f32_16x16x32_bf16(bfr[3], wfrag[i][3], acc, 0, 0, 0);
                    acc_s[i] = acc;
                } else {
                    acc_s[i] = (f32x4){0.f, 0.f, 0.f, 0.f};
                }
            }

            // ---- scalar tile select by bq (3 cndmask)
            float pre = acc_s[0][0];
            pre = (bq == 1) ? acc_s[1][0] : pre;
            pre = (bq == 2) ? acc_s[2][0] : pre;
            pre = (bq == 3) ? acc_s[3][0] : pre;
            pre += xqv[u];

            // ---- unified activation: act = 1 - bsub * rcp(exp(kk2*pre) + 1)
            // g!=2: sigmoid ; g==2: tanh
            const float e = __expf(pre * kk2);
            const float act = fmaf(-bsub, rcp_fast(e + 1.0f), 1.0f);

            // ---- quad combine via DPP (lanes g0=i g1=f g2=g~ g3=o)
            const float prod = act * qb<0xAA>(act);          // lane g0: i * g~
            const float cnew = fmaf(act, c, qb<0x00>(prod)); // lane g1: f*c + i*g~
            c = isg1 ? cnew : c;                             // c lives on g1 lanes
            const float e2 = __expf(c + c);                  // tanh(c) on g1
            const float tc = fmaf(-2.0f, rcp_fast(e2 + 1.0f), 1.0f);
            const float hv = act * qb<0x55>(tc);             // lane g3: o * tanh(c)
            const unsigned short hb = f2bf_fast(hv);

            if (writer) {
                h_lds[1 - cur][unit] = hb;                   // publish
                hs[(size_t)tt * HIDDEN + unit] = hb;         // fire-and-forget bf16
            }
            // depth-4 prefetch; unconditional (reads past xp end spill into the
            // hs region of d_ws -- valid memory, value never consumed)
            xqv[u] = xp[(size_t)(tt + 4) * GATES + pown];

            LDS_BARRIER();   // h visible to all waves for step tt+1
        }
    }
}

// ---------------------------------------------------------------------------
// Kernel 3: out[t] = sigmoid(dot(hs_bf16[t], W_lin) + b_lin)
// ---------------------------------------------------------------------------
__global__ __launch_bounds__(256) void pred_kernel(
    const unsigned short* __restrict__ hs,   // [TSEQ][100] bf16
    const float* __restrict__ wlin,          // [100]
    const float* __restrict__ blin,          // [1]
    float* __restrict__ out)                 // [TSEQ]
{
    __shared__ __align__(16) float wl[HIDDEN];
    const int tid = threadIdx.x;
    if (tid < HIDDEN) wl[tid] = wlin[tid];
    __syncthreads();

    const int t = blockIdx.x * 256 + tid;
    const unsigned short* hrow = hs + (size_t)t * HIDDEN;   // 8B-aligned
    float acc = blin[0];
#pragma unroll
    for (int kk = 0; kk < 25; ++kk) {                       // 25 x uint2 = 100 bf16
        const uint2 v = *(const uint2*)&hrow[kk * 4];
        acc = fmaf(bf2f(v.x & 0xffffu), wl[kk * 4 + 0], acc);
        acc = fmaf(bf2f(v.x >> 16),     wl[kk * 4 + 1], acc);
        acc = fmaf(bf2f(v.y & 0xffffu), wl[kk * 4 + 2], acc);
        acc = fmaf(bf2f(v.y >> 16),     wl[kk * 4 + 3], acc);
    }
    out[t] = sigm(acc);
}

// ---------------------------------------------------------------------------
extern "C" void kernel_launch(void* const* d_in, const int* in_sizes, int n_in,
                              void* d_out, int out_size, void* d_ws, size_t ws_size,
                              hipStream_t stream) {
    const float* x     = (const float*)d_in[0];  // [65536,128]
    const float* W_ih  = (const float*)d_in[1];  // [400,128]
    const float* W_hh  = (const float*)d_in[2];  // [400,100]
    const float* b_ih  = (const float*)d_in[3];  // [400]
    const float* b_hh  = (const float*)d_in[4];  // [400]
    const float* W_lin = (const float*)d_in[5];  // [1,100]
    const float* b_lin = (const float*)d_in[6];  // [1]
    float* out = (float*)d_out;                  // [65536]

    float* xp = (float*)d_ws;                                  // [TSEQ*400] fp32
    unsigned short* hs = (unsigned short*)(xp + (size_t)TSEQ * GATES);  // [TSEQ*100] bf16

    xproj_kernel<<<TSEQ / 16, 256, 0, stream>>>(x, W_ih, b_ih, b_hh, xp);
    lstm_rec_kernel<<<1, 512, 0, stream>>>(xp, W_hh, hs);
    pred_kernel<<<TSEQ / 256, 256, 0, stream>>>(hs, W_lin, b_lin, out);
}